// Round 3
// baseline (542.601 us; speedup 1.0000x reference)
//
#include <hip/hip_runtime.h>

#define B_ 32
#define Q_ 128
#define S_ 2048
#define C_ 1024
#define D_ 1024

typedef __attribute__((ext_vector_type(8))) short bf16x8;
typedef __attribute__((ext_vector_type(4))) float f32x4;

static __device__ __forceinline__ unsigned short f2bf(float f) {
  unsigned int u = __float_as_uint(f);
  u = (u + 0x7FFFu + ((u >> 16) & 1u)) >> 16;
  return (unsigned short)u;
}
static __device__ __forceinline__ float bf2f(unsigned short h) {
  return __uint_as_float(((unsigned int)h) << 16);
}

// Stage 16 consecutive f32 (row r, cols sc..sc+15 of a 64-wide K-tile) into
// hi/lo bf16 LDS tiles [128][64] with XOR-16B swizzle on the 128B row.
static __device__ __forceinline__ void stage16(unsigned short* hi, unsigned short* lo,
                                               const float* s, int r, int sc) {
  float v[16];
#pragma unroll
  for (int j = 0; j < 4; ++j) {
    f32x4 t = *(const f32x4*)(s + j * 4);
    v[j * 4 + 0] = t[0]; v[j * 4 + 1] = t[1]; v[j * 4 + 2] = t[2]; v[j * 4 + 3] = t[3];
  }
  unsigned short h[16], l[16];
#pragma unroll
  for (int e = 0; e < 16; ++e) {
    h[e] = f2bf(v[e]);
    float rres = v[e] - bf2f(h[e]);
    l[e] = f2bf(rres);
  }
  bf16x8 vh0, vh1, vl0, vl1;
#pragma unroll
  for (int e = 0; e < 8; ++e) {
    vh0[e] = (short)h[e]; vh1[e] = (short)h[e + 8];
    vl0[e] = (short)l[e]; vl1[e] = (short)l[e + 8];
  }
  const int swz = (r & 7) << 4;
  char* hrow = (char*)hi + r * 128;
  char* lrow = (char*)lo + r * 128;
  *(bf16x8*)(hrow + (((sc * 2) + 0)  ^ swz)) = vh0;
  *(bf16x8*)(hrow + (((sc * 2) + 16) ^ swz)) = vh1;
  *(bf16x8*)(lrow + (((sc * 2) + 0)  ^ swz)) = vl0;
  *(bf16x8*)(lrow + (((sc * 2) + 16) ^ swz)) = vl1;
}

// C[m,n] = sum_k A[m,k]*B[n,k]; A,B rows K-contiguous.
// SPLIT=true: A,B are f32, split to bf16 hi/lo on the fly, 3-pass MFMA (f32-ish precision).
// SPLIT=false: A,B are bf16 (ushort), single pass.
template <bool SPLIT>
__global__ __launch_bounds__(256, 2)
void gemm_bt(const void* __restrict__ Aip, const void* __restrict__ Bip,
             float* __restrict__ outp, int K,
             long aBatch, long bBatch, long outBatch, long outRstride, int remapQB) {
  extern __shared__ char smem[];
  unsigned short* sA_hi = (unsigned short*)smem;  // [128][64]
  unsigned short* sA_lo = nullptr;
  unsigned short* sB_hi;
  unsigned short* sB_lo = nullptr;
  if constexpr (SPLIT) {
    sA_lo = sA_hi + 128 * 64;
    sB_hi = sA_lo + 128 * 64;
    sB_lo = sB_hi + 128 * 64;
  } else {
    sB_hi = sA_hi + 128 * 64;
  }

  const int tid = threadIdx.x;
  const int lane = tid & 63;
  const int wid = tid >> 6;
  const int wr = wid >> 1;
  const int wc = wid & 1;
  const int m0 = blockIdx.y * 128;
  const int n0 = blockIdx.x * 128;
  const int bz = blockIdx.z;
  const int frow = lane & 15;

  f32x4 acc[4][4];
#pragma unroll
  for (int i = 0; i < 4; ++i)
#pragma unroll
    for (int j = 0; j < 4; ++j) acc[i][j] = (f32x4){0.f, 0.f, 0.f, 0.f};

  for (int kt = 0; kt < K; kt += 64) {
    if constexpr (SPLIT) {
      const float* Af = (const float*)Aip + (long)bz * aBatch;
      const float* Bf = (const float*)Bip + (long)bz * bBatch;
      const int sr = tid >> 2;        // 0..63
      const int sc = (tid & 3) << 4;  // 0,16,32,48 (f32 elements)
#pragma unroll
      for (int p = 0; p < 2; ++p) {
        const int r = sr + (p << 6);
        stage16(sA_hi, sA_lo, Af + (long)(m0 + r) * K + kt + sc, r, sc);
        stage16(sB_hi, sB_lo, Bf + (long)(n0 + r) * K + kt + sc, r, sc);
      }
    } else {
      const unsigned short* Ab = (const unsigned short*)Aip + (long)bz * aBatch;
      const unsigned short* Bb = (const unsigned short*)Bip + (long)bz * bBatch;
      const int r = tid >> 1;
      const int sc = (tid & 1) << 5;  // 0 or 32 (bf16 cols)
      const int swz = (r & 7) << 4;
      {
        const unsigned short* s = Ab + (long)(m0 + r) * K + kt + sc;
        char* row = (char*)sA_hi + r * 128;
#pragma unroll
        for (int j = 0; j < 4; ++j)
          *(bf16x8*)(row + ((sc * 2 + j * 16) ^ swz)) = *(const bf16x8*)(s + j * 8);
      }
      {
        const unsigned short* s = Bb + (long)(n0 + r) * K + kt + sc;
        char* row = (char*)sB_hi + r * 128;
#pragma unroll
        for (int j = 0; j < 4; ++j)
          *(bf16x8*)(row + ((sc * 2 + j * 16) ^ swz)) = *(const bf16x8*)(s + j * 8);
      }
    }
    __syncthreads();

#pragma unroll
    for (int kk = 0; kk < 2; ++kk) {
      const int kb = kk * 64 + ((lane >> 4) << 4);  // byte offset of lane's 16B chunk
      bf16x8 ah[4], bh[4], al[4], bl[4];
#pragma unroll
      for (int i = 0; i < 4; ++i) {
        const int row = wr * 64 + i * 16 + frow;
        const int off = row * 128 + (kb ^ ((row & 7) << 4));
        ah[i] = *(const bf16x8*)((const char*)sA_hi + off);
        if constexpr (SPLIT) al[i] = *(const bf16x8*)((const char*)sA_lo + off);
      }
#pragma unroll
      for (int j = 0; j < 4; ++j) {
        const int row = wc * 64 + j * 16 + frow;
        const int off = row * 128 + (kb ^ ((row & 7) << 4));
        bh[j] = *(const bf16x8*)((const char*)sB_hi + off);
        if constexpr (SPLIT) bl[j] = *(const bf16x8*)((const char*)sB_lo + off);
      }
#pragma unroll
      for (int i = 0; i < 4; ++i)
#pragma unroll
        for (int j = 0; j < 4; ++j) {
          acc[i][j] = __builtin_amdgcn_mfma_f32_16x16x32_bf16(ah[i], bh[j], acc[i][j], 0, 0, 0);
          if constexpr (SPLIT) {
            acc[i][j] = __builtin_amdgcn_mfma_f32_16x16x32_bf16(ah[i], bl[j], acc[i][j], 0, 0, 0);
            acc[i][j] = __builtin_amdgcn_mfma_f32_16x16x32_bf16(al[i], bh[j], acc[i][j], 0, 0, 0);
          }
        }
    }
    __syncthreads();
  }

  float* out = outp + (long)bz * outBatch;
#pragma unroll
  for (int i = 0; i < 4; ++i) {
#pragma unroll
    for (int rr = 0; rr < 4; ++rr) {
      const int grow = m0 + wr * 64 + i * 16 + ((lane >> 4) << 2) + rr;
      const long orow = remapQB ? ((long)(grow & 31) * 128 + (grow >> 5)) : (long)grow;
      float* orp = out + orow * outRstride;
#pragma unroll
      for (int j = 0; j < 4; ++j) {
        const int col = n0 + wc * 64 + j * 16 + (lane & 15);
        orp[col] = acc[i][j][rr];
      }
    }
  }
}

// ctx [B][S][C] f32  ->  ctxT [B][C][S] bf16
__global__ __launch_bounds__(256)
void transpose_ctx(const float* __restrict__ ctx, unsigned short* __restrict__ ctxT) {
  __shared__ float tile[32][33];
  const int b = blockIdx.z;
  const int c0 = blockIdx.x * 32;
  const int s0 = blockIdx.y * 32;
  const int tx = threadIdx.x, ty = threadIdx.y;  // (32, 8)
  const float* src = ctx + ((long)b * S_ + s0) * C_ + c0;
#pragma unroll
  for (int i = ty; i < 32; i += 8) tile[i][tx] = src[(long)i * C_ + tx];
  __syncthreads();
  unsigned short* dst = ctxT + ((long)b * C_ + c0) * S_ + s0;
#pragma unroll
  for (int i = ty; i < 32; i += 8) dst[(long)i * S_ + tx] = f2bf(tile[tx][i]);
}

// ---------------------------------------------------------------------------
// Sequential coverage-softmax scan: ONE WAVE per batch b. 64 lanes x 32
// s-columns/lane, all state in registers, no LDS, no __syncthreads.
// Double-buffered prefetch of next q's score row hides global load latency.
// ---------------------------------------------------------------------------

#define SCAN_INF __builtin_inff()

// Load score row q of batch b into 8 f32x4 regs (lane's columns: ch*256+lane*4).
static __device__ __forceinline__ void scan_load(const float* __restrict__ attn,
                                                 int b, int q, int lane, f32x4* buf) {
  const float* p = attn + ((long)(q * B_ + b)) * S_ + lane * 4;
#pragma unroll
  for (int ch = 0; ch < 8; ++ch) buf[ch] = *(const f32x4*)(p + ch * 256);
}

static __device__ __forceinline__ void scan_process(
    const f32x4* buf, unsigned int mbits, float* acc,
    float* __restrict__ attn, unsigned short* __restrict__ attnb,
    int b, int q, int lane) {
  float ev[32];
  // adjusted scores (masked -> -inf)
#pragma unroll
  for (int ch = 0; ch < 8; ++ch)
#pragma unroll
    for (int j = 0; j < 4; ++j) {
      const int i = ch * 4 + j;
      ev[i] = ((mbits >> i) & 1u) ? -SCAN_INF : (buf[ch][j] - acc[i]);
    }

  // lane-local max (tree)
  float t16[16], t8[8], t4[4], t2[2];
#pragma unroll
  for (int i = 0; i < 16; ++i) t16[i] = fmaxf(ev[i], ev[i + 16]);
#pragma unroll
  for (int i = 0; i < 8; ++i) t8[i] = fmaxf(t16[i], t16[i + 8]);
#pragma unroll
  for (int i = 0; i < 4; ++i) t4[i] = fmaxf(t8[i], t8[i + 4]);
  t2[0] = fmaxf(t4[0], t4[2]); t2[1] = fmaxf(t4[1], t4[3]);
  float mx = fmaxf(t2[0], t2[1]);
  // wave-wide max
#pragma unroll
  for (int off = 32; off > 0; off >>= 1) mx = fmaxf(mx, __shfl_xor(mx, off));

  // exp
#pragma unroll
  for (int i = 0; i < 32; ++i)
    ev[i] = exp2f((ev[i] - mx) * 1.4426950408889634f);

  // lane-local sum (tree)
  float s16[16], s8[8], s4[4];
#pragma unroll
  for (int i = 0; i < 16; ++i) s16[i] = ev[i] + ev[i + 16];
#pragma unroll
  for (int i = 0; i < 8; ++i) s8[i] = s16[i] + s16[i + 8];
#pragma unroll
  for (int i = 0; i < 4; ++i) s4[i] = s8[i] + s8[i + 4];
  float sum = (s4[0] + s4[1]) + (s4[2] + s4[3]);
#pragma unroll
  for (int off = 32; off > 0; off >>= 1) sum += __shfl_xor(sum, off);
  const float inv = 1.0f / sum;

  float* arow = attn + ((long)(q * B_ + b)) * S_ + lane * 4;
  unsigned short* brow = attnb + ((long)b * Q_ + q) * S_ + lane * 4;
#pragma unroll
  for (int ch = 0; ch < 8; ++ch) {
    f32x4 av;
#pragma unroll
    for (int j = 0; j < 4; ++j) {
      const int i = ch * 4 + j;
      const float a = ev[i] * inv;
      av[j] = a;
      acc[i] += a;
    }
    *(f32x4*)(arow + ch * 256) = av;
    *(ushort4*)(brow + ch * 256) = make_ushort4(f2bf(av[0]), f2bf(av[1]), f2bf(av[2]), f2bf(av[3]));
  }
}

__global__ __launch_bounds__(64)
void scan_kernel(const int* __restrict__ mask, float* __restrict__ attn,
                 float* __restrict__ accum_out, unsigned short* __restrict__ attnb) {
  const int b = blockIdx.x;
  const int lane = threadIdx.x;

  // mask bits: bit i = column ch*4+j (s = ch*256 + lane*4 + j)
  unsigned int mbits = 0;
#pragma unroll
  for (int ch = 0; ch < 8; ++ch) {
    const int4 mk = *(const int4*)(mask + (long)b * S_ + ch * 256 + lane * 4);
    if (mk.x) mbits |= 1u << (ch * 4 + 0);
    if (mk.y) mbits |= 1u << (ch * 4 + 1);
    if (mk.z) mbits |= 1u << (ch * 4 + 2);
    if (mk.w) mbits |= 1u << (ch * 4 + 3);
  }

  float acc[32];
#pragma unroll
  for (int i = 0; i < 32; ++i) acc[i] = 0.f;

  f32x4 bufA[8], bufB[8];
  scan_load(attn, b, 0, lane, bufA);

  for (int q = 0; q < Q_; q += 2) {
    scan_load(attn, b, q + 1, lane, bufB);       // prefetch q+1 (q+1 <= 127)
    scan_process(bufA, mbits, acc, attn, attnb, b, q, lane);
    if (q + 2 < Q_) scan_load(attn, b, q + 2, lane, bufA);  // prefetch q+2
    scan_process(bufB, mbits, acc, attn, attnb, b, q + 1, lane);
  }

  float* aout = accum_out + (long)b * S_ + lane * 4;
#pragma unroll
  for (int ch = 0; ch < 8; ++ch) {
    f32x4 a4;
#pragma unroll
    for (int j = 0; j < 4; ++j) a4[j] = acc[ch * 4 + j];
    *(f32x4*)(aout + ch * 256) = a4;
  }
}

extern "C" void kernel_launch(void* const* d_in, const int* in_sizes, int n_in,
                              void* d_out, int out_size, void* d_ws, size_t ws_size,
                              hipStream_t stream) {
  const float* ctx   = (const float*)d_in[0];  // [B,S,C] f32
  const float* query = (const float*)d_in[1];  // [Q,B,D] f32
  const int*   mask  = (const int*)d_in[2];    // [B,S] int32 (bool)
  const float* W     = (const float*)d_in[3];  // [C,D] f32

  float* out = (float*)d_out;
  float* attn = out;                                      // [Q,B,S]
  float* accum_out = out + (size_t)Q_ * B_ * S_;          // [B,1,S]
  float* comp = accum_out + (size_t)B_ * S_;              // [Q,B,C]

  char* ws = (char*)d_ws;
  float* qw = (float*)ws;                                                // [B,Q,C] f32, 16 MiB
  unsigned short* ctxT  = (unsigned short*)(ws + (size_t)16 * 1024 * 1024);             // [B,C,S] bf16, 128 MiB
  unsigned short* attnb = (unsigned short*)(ws + (size_t)16 * 1024 * 1024 +
                                            (size_t)B_ * C_ * S_ * 2);   // [B,Q,S] bf16, 16 MiB

  // 1) ctx -> ctxT (bf16, transposed) for the composition GEMM
  transpose_ctx<<<dim3(C_ / 32, S_ / 32, B_), dim3(32, 8), 0, stream>>>(ctx, ctxT);

  // 2) QW[b,q,c] = sum_d query[q,b,d] * W[c,d]   (3-pass split for precision)
  gemm_bt<true><<<dim3(C_ / 128, (Q_ * B_) / 128, 1), 256, 65536, stream>>>(
      query, W, qw, D_, 0L, 0L, 0L, (long)C_, 1);

  // 3) scores[q,b,s] = sum_c QW[b,q,c] * ctx[b,s,c]  -> attention region of d_out
  gemm_bt<true><<<dim3(S_ / 128, 1, B_), 256, 65536, stream>>>(
      qw, ctx, attn, C_, (long)Q_ * C_, (long)S_ * C_, (long)S_, (long)B_ * S_, 0);

  // 4) sequential coverage-softmax scan (in-place attention + accum + bf16 copy)
  scan_kernel<<<B_, 64, 0, stream>>>(mask, attn, accum_out, attnb);

  // 5) composition[q,b,c] = sum_s attn[q,b,s] * ctx[b,s,c]
  gemm_bt<false><<<dim3(C_ / 128, 1, B_), 256, 32768, stream>>>(
      attnb, ctxT, comp, S_, (long)Q_ * S_, (long)C_ * S_, (long)C_, (long)B_ * C_, 0);
}

// Round 6
// 473.778 us; speedup vs baseline: 1.1453x; 1.1453x over previous
//
#include <hip/hip_runtime.h>

#define B_ 32
#define Q_ 128
#define S_ 2048
#define C_ 1024
#define D_ 1024

typedef __attribute__((ext_vector_type(8))) short bf16x8;
typedef __attribute__((ext_vector_type(4))) float f32x4;

static __device__ __forceinline__ unsigned short f2bf(float f) {
  unsigned int u = __float_as_uint(f);
  u = (u + 0x7FFFu + ((u >> 16) & 1u)) >> 16;
  return (unsigned short)u;
}
static __device__ __forceinline__ float bf2f(unsigned short h) {
  return __uint_as_float(((unsigned int)h) << 16);
}

// Stage 16 consecutive f32 (row r, cols sc..sc+15 of a 64-wide K-tile) into
// hi/lo bf16 LDS tiles [128][64] with XOR-16B swizzle on the 128B row.
static __device__ __forceinline__ void stage16(unsigned short* hi, unsigned short* lo,
                                               const float* s, int r, int sc) {
  float v[16];
#pragma unroll
  for (int j = 0; j < 4; ++j) {
    f32x4 t = *(const f32x4*)(s + j * 4);
    v[j * 4 + 0] = t[0]; v[j * 4 + 1] = t[1]; v[j * 4 + 2] = t[2]; v[j * 4 + 3] = t[3];
  }
  unsigned short h[16], l[16];
#pragma unroll
  for (int e = 0; e < 16; ++e) {
    h[e] = f2bf(v[e]);
    float rres = v[e] - bf2f(h[e]);
    l[e] = f2bf(rres);
  }
  bf16x8 vh0, vh1, vl0, vl1;
#pragma unroll
  for (int e = 0; e < 8; ++e) {
    vh0[e] = (short)h[e]; vh1[e] = (short)h[e + 8];
    vl0[e] = (short)l[e]; vl1[e] = (short)l[e + 8];
  }
  const int swz = (r & 7) << 4;
  char* hrow = (char*)hi + r * 128;
  char* lrow = (char*)lo + r * 128;
  *(bf16x8*)(hrow + (((sc * 2) + 0)  ^ swz)) = vh0;
  *(bf16x8*)(hrow + (((sc * 2) + 16) ^ swz)) = vh1;
  *(bf16x8*)(lrow + (((sc * 2) + 0)  ^ swz)) = vl0;
  *(bf16x8*)(lrow + (((sc * 2) + 16) ^ swz)) = vl1;
}

// C[m,n] = sum_k A[m,k]*B[n,k]; A,B rows K-contiguous.
// SPLIT=true: A,B are f32, split to bf16 hi/lo on the fly, 3-pass MFMA (f32-ish precision).
// SPLIT=false: A,B are bf16 (ushort), single pass.
template <bool SPLIT>
__global__ __launch_bounds__(256, 2)
void gemm_bt(const void* __restrict__ Aip, const void* __restrict__ Bip,
             float* __restrict__ outp, int K,
             long aBatch, long bBatch, long outBatch, long outRstride, int remapQB) {
  extern __shared__ char smem[];
  unsigned short* sA_hi = (unsigned short*)smem;  // [128][64]
  unsigned short* sA_lo = nullptr;
  unsigned short* sB_hi;
  unsigned short* sB_lo = nullptr;
  if constexpr (SPLIT) {
    sA_lo = sA_hi + 128 * 64;
    sB_hi = sA_lo + 128 * 64;
    sB_lo = sB_hi + 128 * 64;
  } else {
    sB_hi = sA_hi + 128 * 64;
  }

  const int tid = threadIdx.x;
  const int lane = tid & 63;
  const int wid = tid >> 6;
  const int wr = wid >> 1;
  const int wc = wid & 1;
  const int m0 = blockIdx.y * 128;
  const int n0 = blockIdx.x * 128;
  const int bz = blockIdx.z;
  const int frow = lane & 15;

  f32x4 acc[4][4];
#pragma unroll
  for (int i = 0; i < 4; ++i)
#pragma unroll
    for (int j = 0; j < 4; ++j) acc[i][j] = (f32x4){0.f, 0.f, 0.f, 0.f};

  for (int kt = 0; kt < K; kt += 64) {
    if constexpr (SPLIT) {
      const float* Af = (const float*)Aip + (long)bz * aBatch;
      const float* Bf = (const float*)Bip + (long)bz * bBatch;
      const int sr = tid >> 2;        // 0..63
      const int sc = (tid & 3) << 4;  // 0,16,32,48 (f32 elements)
#pragma unroll
      for (int p = 0; p < 2; ++p) {
        const int r = sr + (p << 6);
        stage16(sA_hi, sA_lo, Af + (long)(m0 + r) * K + kt + sc, r, sc);
        stage16(sB_hi, sB_lo, Bf + (long)(n0 + r) * K + kt + sc, r, sc);
      }
    } else {
      const unsigned short* Ab = (const unsigned short*)Aip + (long)bz * aBatch;
      const unsigned short* Bb = (const unsigned short*)Bip + (long)bz * bBatch;
      const int r = tid >> 1;
      const int sc = (tid & 1) << 5;  // 0 or 32 (bf16 cols)
      const int swz = (r & 7) << 4;
      {
        const unsigned short* s = Ab + (long)(m0 + r) * K + kt + sc;
        char* row = (char*)sA_hi + r * 128;
#pragma unroll
        for (int j = 0; j < 4; ++j)
          *(bf16x8*)(row + ((sc * 2 + j * 16) ^ swz)) = *(const bf16x8*)(s + j * 8);
      }
      {
        const unsigned short* s = Bb + (long)(n0 + r) * K + kt + sc;
        char* row = (char*)sB_hi + r * 128;
#pragma unroll
        for (int j = 0; j < 4; ++j)
          *(bf16x8*)(row + ((sc * 2 + j * 16) ^ swz)) = *(const bf16x8*)(s + j * 8);
      }
    }
    __syncthreads();

#pragma unroll
    for (int kk = 0; kk < 2; ++kk) {
      const int kb = kk * 64 + ((lane >> 4) << 4);  // byte offset of lane's 16B chunk
      bf16x8 ah[4], bh[4], al[4], bl[4];
#pragma unroll
      for (int i = 0; i < 4; ++i) {
        const int row = wr * 64 + i * 16 + frow;
        const int off = row * 128 + (kb ^ ((row & 7) << 4));
        ah[i] = *(const bf16x8*)((const char*)sA_hi + off);
        if constexpr (SPLIT) al[i] = *(const bf16x8*)((const char*)sA_lo + off);
      }
#pragma unroll
      for (int j = 0; j < 4; ++j) {
        const int row = wc * 64 + j * 16 + frow;
        const int off = row * 128 + (kb ^ ((row & 7) << 4));
        bh[j] = *(const bf16x8*)((const char*)sB_hi + off);
        if constexpr (SPLIT) bl[j] = *(const bf16x8*)((const char*)sB_lo + off);
      }
#pragma unroll
      for (int i = 0; i < 4; ++i)
#pragma unroll
        for (int j = 0; j < 4; ++j) {
          acc[i][j] = __builtin_amdgcn_mfma_f32_16x16x32_bf16(ah[i], bh[j], acc[i][j], 0, 0, 0);
          if constexpr (SPLIT) {
            acc[i][j] = __builtin_amdgcn_mfma_f32_16x16x32_bf16(ah[i], bl[j], acc[i][j], 0, 0, 0);
            acc[i][j] = __builtin_amdgcn_mfma_f32_16x16x32_bf16(al[i], bh[j], acc[i][j], 0, 0, 0);
          }
        }
    }
    __syncthreads();
  }

  float* out = outp + (long)bz * outBatch;
#pragma unroll
  for (int i = 0; i < 4; ++i) {
#pragma unroll
    for (int rr = 0; rr < 4; ++rr) {
      const int grow = m0 + wr * 64 + i * 16 + ((lane >> 4) << 2) + rr;
      const long orow = remapQB ? ((long)(grow & 31) * 128 + (grow >> 5)) : (long)grow;
      float* orp = out + orow * outRstride;
#pragma unroll
      for (int j = 0; j < 4; ++j) {
        const int col = n0 + wc * 64 + j * 16 + (lane & 15);
        orp[col] = acc[i][j][rr];
      }
    }
  }
}

// ctx [B][S][C] f32  ->  ctxT [B][C][S] bf16
__global__ __launch_bounds__(256)
void transpose_ctx(const float* __restrict__ ctx, unsigned short* __restrict__ ctxT) {
  __shared__ float tile[32][33];
  const int b = blockIdx.z;
  const int c0 = blockIdx.x * 32;
  const int s0 = blockIdx.y * 32;
  const int tx = threadIdx.x, ty = threadIdx.y;  // (32, 8)
  const float* src = ctx + ((long)b * S_ + s0) * C_ + c0;
#pragma unroll
  for (int i = ty; i < 32; i += 8) tile[i][tx] = src[(long)i * C_ + tx];
  __syncthreads();
  unsigned short* dst = ctxT + ((long)b * C_ + c0) * S_ + s0;
#pragma unroll
  for (int i = ty; i < 32; i += 8) dst[(long)i * S_ + tx] = f2bf(tile[tx][i]);
}

// ---------------------------------------------------------------------------
// Sequential coverage-softmax scan. 512 threads/block (8 waves), 4 cols/thread.
// EXACT per-row masked max (round-2 math, which passed), with two mechanical
// scheduling improvements only:
//  - register prefetch of row q+1 before processing row q (latency hiding)
//  - parity double-buffered LDS reduction slots -> 2 barriers/row instead of 3
//    (write to parity p at iter q+2 is ordered after barrier B(q+1), which
//    happens-after every wave's reads of parity p at iter q)
// Numerics: finite sentinel -1e30, masked e force-selected to 0, exact max
// => tot >= 1 (argmax element contributes exp(0)=1), precise 1/tot.
// Separate (non-interleaved) shuffle-reduction loops for max and sum.
// ---------------------------------------------------------------------------
__global__ __launch_bounds__(512)
void scan_kernel(const int* __restrict__ mask, float* __restrict__ attn,
                 float* __restrict__ accum_out, unsigned short* __restrict__ attnb) {
  const int b = blockIdx.x;
  const int tid = threadIdx.x;   // 0..511
  const int lane = tid & 63;
  const int wid = tid >> 6;      // 0..7
  const int s0 = tid * 4;

  __shared__ float redm[2][8];
  __shared__ float reds[2][8];

  const int4 mk = *(const int4*)(mask + (long)b * S_ + s0);
  const bool msk[4] = {mk.x != 0, mk.y != 0, mk.z != 0, mk.w != 0};

  float acc[4] = {0.f, 0.f, 0.f, 0.f};

  // row 0 (scores for q=0 live at row index b of attn)
  f32x4 cur = *(const f32x4*)(attn + (long)b * S_ + s0);

  for (int q = 0; q < Q_; ++q) {
    const int p = q & 1;

    // prefetch next row into registers (own columns only; row q+1 is not
    // written until iteration q+1, so no cross-thread dependency)
    f32x4 nxt = cur;
    if (q + 1 < Q_) nxt = *(const f32x4*)(attn + ((long)((q + 1) * B_ + b)) * S_ + s0);

    // adjusted scores
    float adj[4];
#pragma unroll
    for (int j = 0; j < 4; ++j)
      adj[j] = msk[j] ? -1e30f : (cur[j] - acc[j]);

    // exact masked row max: lane tree + wave butterfly (separate loop)
    float lm = fmaxf(fmaxf(adj[0], adj[1]), fmaxf(adj[2], adj[3]));
#pragma unroll
    for (int off = 32; off > 0; off >>= 1) lm = fmaxf(lm, __shfl_xor(lm, off));
    if (lane == 0) redm[p][wid] = lm;
    __syncthreads();  // barrier A
    float mx = redm[p][0];
#pragma unroll
    for (int w = 1; w < 8; ++w) mx = fmaxf(mx, redm[p][w]);

    // exp with exact shift; masked entries force-selected to 0
    float e[4];
#pragma unroll
    for (int j = 0; j < 4; ++j)
      e[j] = msk[j] ? 0.f : exp2f((adj[j] - mx) * 1.4426950408889634f);

    // sum: lane tree + wave butterfly (separate loop)
    float ls = (e[0] + e[1]) + (e[2] + e[3]);
#pragma unroll
    for (int off = 32; off > 0; off >>= 1) ls += __shfl_xor(ls, off);
    if (lane == 0) reds[p][wid] = ls;
    __syncthreads();  // barrier B
    float tot = reds[p][0];
#pragma unroll
    for (int w = 1; w < 8; ++w) tot += reds[p][w];
    const float inv = 1.0f / tot;  // tot >= 1: exact max guarantees argmax e == 1

    f32x4 av;
#pragma unroll
    for (int j = 0; j < 4; ++j) {
      av[j] = e[j] * inv;
      acc[j] += av[j];
    }
    *(f32x4*)(attn + ((long)(q * B_ + b)) * S_ + s0) = av;
    *(ushort4*)(attnb + ((long)b * Q_ + q) * S_ + s0) =
        make_ushort4(f2bf(av[0]), f2bf(av[1]), f2bf(av[2]), f2bf(av[3]));

    cur = nxt;
  }

  f32x4 a4;
#pragma unroll
  for (int j = 0; j < 4; ++j) a4[j] = acc[j];
  *(f32x4*)(accum_out + (long)b * S_ + s0) = a4;
}

extern "C" void kernel_launch(void* const* d_in, const int* in_sizes, int n_in,
                              void* d_out, int out_size, void* d_ws, size_t ws_size,
                              hipStream_t stream) {
  const float* ctx   = (const float*)d_in[0];  // [B,S,C] f32
  const float* query = (const float*)d_in[1];  // [Q,B,D] f32
  const int*   mask  = (const int*)d_in[2];    // [B,S] int32 (bool)
  const float* W     = (const float*)d_in[3];  // [C,D] f32

  float* out = (float*)d_out;
  float* attn = out;                                      // [Q,B,S]
  float* accum_out = out + (size_t)Q_ * B_ * S_;          // [B,1,S]
  float* comp = accum_out + (size_t)B_ * S_;              // [Q,B,C]

  char* ws = (char*)d_ws;
  float* qw = (float*)ws;                                                // [B,Q,C] f32, 16 MiB
  unsigned short* ctxT  = (unsigned short*)(ws + (size_t)16 * 1024 * 1024);             // [B,C,S] bf16, 128 MiB
  unsigned short* attnb = (unsigned short*)(ws + (size_t)16 * 1024 * 1024 +
                                            (size_t)B_ * C_ * S_ * 2);   // [B,Q,S] bf16, 16 MiB

  // 1) ctx -> ctxT (bf16, transposed) for the composition GEMM
  transpose_ctx<<<dim3(C_ / 32, S_ / 32, B_), dim3(32, 8), 0, stream>>>(ctx, ctxT);

  // 2) QW[b,q,c] = sum_d query[q,b,d] * W[c,d]   (3-pass split for precision)
  gemm_bt<true><<<dim3(C_ / 128, (Q_ * B_) / 128, 1), 256, 65536, stream>>>(
      query, W, qw, D_, 0L, 0L, 0L, (long)C_, 1);

  // 3) scores[q,b,s] = sum_c QW[b,q,c] * ctx[b,s,c]  -> attention region of d_out
  gemm_bt<true><<<dim3(S_ / 128, 1, B_), 256, 65536, stream>>>(
      qw, ctx, attn, C_, (long)Q_ * C_, (long)S_ * C_, (long)S_, (long)B_ * S_, 0);

  // 4) sequential coverage-softmax scan (in-place attention + accum + bf16 copy)
  scan_kernel<<<B_, 512, 0, stream>>>(mask, attn, accum_out, attnb);

  // 5) composition[q,b,c] = sum_s attn[q,b,s] * ctx[b,s,c]
  gemm_bt<false><<<dim3(C_ / 128, 1, B_), 256, 32768, stream>>>(
      attnb, ctxT, comp, S_, (long)Q_ * S_, (long)C_ * S_, (long)C_, (long)B_ * C_, 0);
}